// Round 1
// 660.251 us; speedup vs baseline: 1.3405x; 1.3405x over previous
//
#include <hip/hip_runtime.h>
#include <hip/hip_bf16.h>
#include <stdint.h>

// Problem constants
#define B_   4
#define S_   4096
#define D_   1280
#define H_   20
#define HD_  64
#define SKV_ 77
#define CD_  2048

typedef short bfrag8 __attribute__((ext_vector_type(8)));   // 8 bf16 = 4 VGPRs
typedef float f32x4  __attribute__((ext_vector_type(4)));

__device__ __forceinline__ float bf2f(unsigned short h) {
  return __uint_as_float(((unsigned int)h) << 16);
}
__device__ __forceinline__ unsigned short f2bf(float f) {
  unsigned int u = __float_as_uint(f);
  unsigned int r = (u + 0x7FFFu + ((u >> 16) & 1u)) >> 16;  // RNE
  return (unsigned short)r;
}
__device__ __forceinline__ float cvtlo(unsigned int u) { return __uint_as_float(u << 16); }
__device__ __forceinline__ float cvthi(unsigned int u) { return __uint_as_float(u & 0xFFFF0000u); }

// async global->LDS, 16B per lane. LDS dest = wave-uniform base + lane*16,
// which our chunk mapping (c = i*256 + tid, lds off = c*16) satisfies.
__device__ __forceinline__ void async16(const unsigned short* g, unsigned short* l) {
  __builtin_amdgcn_global_load_lds(
      (const __attribute__((address_space(1))) unsigned int*)g,
      (__attribute__((address_space(3))) unsigned int*)l, 16, 0, 0);
}

// ---------------------------------------------------------------------------
// fp32 -> bf16 conversion (vectorized)
// ---------------------------------------------------------------------------
__global__ __launch_bounds__(256) void convert_k(const float* __restrict__ src,
                                                 unsigned short* __restrict__ dst,
                                                 int n4) {
  for (int i = blockIdx.x * 256 + threadIdx.x; i < n4; i += gridDim.x * 256) {
    float4 v = ((const float4*)src)[i];
    uint2 o;
    o.x = (unsigned int)f2bf(v.x) | ((unsigned int)f2bf(v.y) << 16);
    o.y = (unsigned int)f2bf(v.z) | ((unsigned int)f2bf(v.w) << 16);
    ((uint2*)dst)[i] = o;
  }
}

// ---------------------------------------------------------------------------
// fp32 [K,N] -> bf16 transposed [N,K], 32x32 LDS tile (both sides coalesced)
// ---------------------------------------------------------------------------
__global__ __launch_bounds__(256) void convtr_k(const float* __restrict__ src,
                                                unsigned short* __restrict__ dst,
                                                int K, int N) {
  __shared__ float t[32][33];
  const int k0 = blockIdx.x * 32, n0 = blockIdx.y * 32;
  const int r = threadIdx.x >> 3, c4 = threadIdx.x & 7;
  float4 v = *(const float4*)(src + (size_t)(k0 + r) * N + n0 + c4 * 4);
  t[r][c4 * 4 + 0] = v.x; t[r][c4 * 4 + 1] = v.y;
  t[r][c4 * 4 + 2] = v.z; t[r][c4 * 4 + 3] = v.w;
  __syncthreads();
  uint2 o;
  o.x = (unsigned int)f2bf(t[c4 * 4 + 0][r]) | ((unsigned int)f2bf(t[c4 * 4 + 1][r]) << 16);
  o.y = (unsigned int)f2bf(t[c4 * 4 + 2][r]) | ((unsigned int)f2bf(t[c4 * 4 + 3][r]) << 16);
  *(uint2*)(dst + (size_t)(n0 + r) * K + k0 + c4 * 4) = o;
}

// ---------------------------------------------------------------------------
// boost scalar
// ---------------------------------------------------------------------------
__global__ __launch_bounds__(256) void boost_k(const float* __restrict__ mask,
                                               float* __restrict__ outp) {
  __shared__ float red[4];
  float s = 0.f;
  for (int i = threadIdx.x; i < S_; i += 256) s += mask[i];
#pragma unroll
  for (int off = 32; off > 0; off >>= 1) s += __shfl_down(s, off, 64);
  int wave = threadIdx.x >> 6, lane = threadIdx.x & 63;
  if (lane == 0) red[wave] = s;
  __syncthreads();
  if (threadIdx.x == 0) {
    float t = red[0] + red[1] + red[2] + red[3];
    float ratio = t * (1.0f / (float)S_);
    float boost = (ratio > 1e-6f && ratio < 0.1f)
                      ? fminf(1.0f + (0.1f - ratio) * 30.0f, 4.0f)
                      : 1.0f;
    outp[0] = boost;
  }
}

// ---------------------------------------------------------------------------
// m97-style GEMM: C[M,N] = A[M,K] @ Bt[N,K]^T (+bias). 128x128 tile, BK=32,
// global_load_lds width-16 staging, 4 waves each computing 64x64 (4x4 MFMA).
// Requires M%128==0, N%128==0, K%32==0 (true for all call sites).
// ---------------------------------------------------------------------------
__global__ __launch_bounds__(256) void gemm_bt128(
    const unsigned short* __restrict__ A, const unsigned short* __restrict__ Bt,
    void* __restrict__ C, int M, int N, int K,
    const float* __restrict__ bias, int f32out) {
  __shared__ unsigned short As[128 * 32];  // 8 KB, unpadded (global_load_lds order)
  __shared__ unsigned short Bs[128 * 32];  // 8 KB, rows = n

  const int tid = threadIdx.x;
  const int m0 = blockIdx.x * 128, n0 = blockIdx.y * 128;
  const int wave = tid >> 6, lane = tid & 63;
  const int wm = (wave >> 1) * 64, wn = (wave & 1) * 64;
  const int l16 = lane & 15, quad = lane >> 4;

  f32x4 acc[4][4] = {};

  for (int k0 = 0; k0 < K; k0 += 32) {
#pragma unroll
    for (int i = 0; i < 2; ++i) {
      int c = i * 256 + tid;
      int r = c >> 2, kc = c & 3;
      async16(A + (size_t)(m0 + r) * K + k0 + kc * 8, As + c * 8);
      async16(Bt + (size_t)(n0 + r) * K + k0 + kc * 8, Bs + c * 8);
    }
    __syncthreads();

    bfrag8 af[4], bf[4];
#pragma unroll
    for (int t = 0; t < 4; ++t) {
      af[t] = *(const bfrag8*)(As + (wm + t * 16 + l16) * 32 + quad * 8);
      bf[t] = *(const bfrag8*)(Bs + (wn + t * 16 + l16) * 32 + quad * 8);
    }
#pragma unroll
    for (int mt = 0; mt < 4; ++mt)
#pragma unroll
      for (int nt = 0; nt < 4; ++nt)
        acc[mt][nt] =
            __builtin_amdgcn_mfma_f32_16x16x32_bf16(af[mt], bf[nt], acc[mt][nt], 0, 0, 0);
    __syncthreads();
  }

  // D layout: row = quad*4 + r, col = lane&15
#pragma unroll
  for (int mt = 0; mt < 4; ++mt) {
#pragma unroll
    for (int nt = 0; nt < 4; ++nt) {
#pragma unroll
      for (int r = 0; r < 4; ++r) {
        int row = m0 + wm + mt * 16 + quad * 4 + r;
        int col = n0 + wn + nt * 16 + l16;
        float v = acc[mt][nt][r];
        if (bias) v += bias[col];
        if (f32out) ((float*)C)[(size_t)row * N + col] = v;
        else ((unsigned short*)C)[(size_t)row * N + col] = f2bf(v);
      }
    }
  }
}

// ---------------------------------------------------------------------------
// small GEMM for KV projections (M=308): 64x64 tile, bounds-checked M.
// ---------------------------------------------------------------------------
__global__ __launch_bounds__(256) void gemm_bf16(
    const unsigned short* __restrict__ A, const unsigned short* __restrict__ Bw,
    unsigned short* __restrict__ C, int M, int N, int K) {
  __shared__ unsigned short As[64][40];
  __shared__ unsigned short Bs[64][40];

  const int tid = threadIdx.x;
  const int m0 = blockIdx.x * 64, n0 = blockIdx.y * 64;
  const int wave = tid >> 6, lane = tid & 63;
  const int l16 = lane & 15, quad = lane >> 4;

  f32x4 acc[4] = {};

  for (int k0 = 0; k0 < K; k0 += 32) {
    {
      int row = tid >> 2, kc = tid & 3;
      int gr = m0 + row;
      uint4 v = make_uint4(0u, 0u, 0u, 0u);
      if (gr < M) v = *(const uint4*)(A + (size_t)gr * K + k0 + kc * 8);
      *(uint4*)&As[row][kc * 8] = v;
    }
    {
      int kk = tid >> 3, n8 = tid & 7;
      uint4 v = *(const uint4*)(Bw + (size_t)(k0 + kk) * N + n0 + n8 * 8);
      unsigned short* p = (unsigned short*)&v;
#pragma unroll
      for (int j = 0; j < 8; ++j) Bs[n8 * 8 + j][kk] = p[j];
    }
    __syncthreads();

    bfrag8 af = *(const bfrag8*)&As[wave * 16 + l16][quad * 8];
#pragma unroll
    for (int nt = 0; nt < 4; ++nt) {
      bfrag8 bf = *(const bfrag8*)&Bs[nt * 16 + l16][quad * 8];
      acc[nt] = __builtin_amdgcn_mfma_f32_16x16x32_bf16(af, bf, acc[nt], 0, 0, 0);
    }
    __syncthreads();
  }

#pragma unroll
  for (int nt = 0; nt < 4; ++nt) {
#pragma unroll
    for (int r = 0; r < 4; ++r) {
      int row = m0 + wave * 16 + quad * 4 + r;
      if (row < M) {
        int col = n0 + nt * 16 + l16;
        C[(size_t)row * N + col] = f2bf(acc[nt][r]);
      }
    }
  }
}

// ---------------------------------------------------------------------------
// Attention v4: MFMA-based. One block = 64 q-rows of one (b,h); 4 waves, each
// wave owns 16 q-rows. SKV=77 padded to 80 (scores) / 96 (PV k-steps).
//
// Scores (swapped): ST[k][q] tile t: mfma(Kfrag[t], Qfrag) -> lane holds
//   col q = lane&15, rows k = 16t + quad*4 + r  (20 scores per lane, full row)
// Softmax: in-lane max/sum over 20 + shfl_xor(16,32) across quads.
// P (unnormalized exp, bf16) -> per-wave LDS tile [16][104], then
// PV: out[q][d] tile dt: mfma(Pfrag, VTfrag[dt]) over 3 k-steps of 32.
// 1/l applied post-MFMA (one shfl per output row). Both branches staged
// up front: LDS = 2*K(80x88) + 2*VT(64x104) + P(4x16x104) = 68,096 B.
// ---------------------------------------------------------------------------
__global__ __launch_bounds__(256, 2) void attn_k(
    const unsigned short* __restrict__ Q, const unsigned short* __restrict__ Kb,
    const unsigned short* __restrict__ Vb, const unsigned short* __restrict__ Kip,
    const unsigned short* __restrict__ Vip, const float* __restrict__ mask,
    const float* __restrict__ boostp, unsigned short* __restrict__ hs) {
  __shared__ unsigned short Ks0[80 * 88];    // 14080 B, row k stride 88 (2-way max)
  __shared__ unsigned short Ks1[80 * 88];
  __shared__ unsigned short VT0[64 * 104];   // 13312 B, row d stride 104 (2-way max)
  __shared__ unsigned short VT1[64 * 104];
  __shared__ unsigned short Ps[4 * 16 * 104];  // per-wave P tile [16 q][104 k]

  const int tid = threadIdx.x;
  const int bh = blockIdx.y;
  const int b = bh / H_, h = bh % H_;
  const int qb = blockIdx.x * 64;
  const int wave = tid >> 6, lane = tid & 63;
  const int l16 = lane & 15, quad = lane >> 4;

  // Q fragment (B-operand): row q = l16 within wave tile, k-chunk = ks*32 + quad*8
  bfrag8 qf[2];
  {
    const unsigned short* qp =
        Q + (size_t)(b * S_ + qb + wave * 16 + l16) * D_ + h * HD_ + quad * 8;
    qf[0] = *(const bfrag8*)(qp);
    qf[1] = *(const bfrag8*)(qp + 32);
  }

  // ---- stage K (rows 0..79, zeros >=77) and V^T (d rows, k 0..95, zeros >=77)
  auto stageK = [&](const unsigned short* src, unsigned short* dst) {
    for (int idx = tid; idx < 640; idx += 256) {
      int row = idx >> 3, c = idx & 7;
      uint4 v = make_uint4(0u, 0u, 0u, 0u);
      if (row < SKV_)
        v = *(const uint4*)(src + (size_t)(b * SKV_ + row) * D_ + h * HD_ + c * 8);
      *(uint4*)(dst + row * 88 + c * 8) = v;
    }
  };
  auto stageVT = [&](const unsigned short* src, unsigned short* dst) {
    for (int idx = tid; idx < 384; idx += 256) {
      int kp = idx % 48, c = idx / 48;  // kp: k-pair 0..47 (k0=2kp up to 94), c: d-chunk
      int k0 = kp * 2;
      uint4 a = make_uint4(0u, 0u, 0u, 0u), bb = make_uint4(0u, 0u, 0u, 0u);
      if (k0 < SKV_)
        a = *(const uint4*)(src + (size_t)(b * SKV_ + k0) * D_ + h * HD_ + c * 8);
      if (k0 + 1 < SKV_)
        bb = *(const uint4*)(src + (size_t)(b * SKV_ + k0 + 1) * D_ + h * HD_ + c * 8);
      const unsigned short* ap = (const unsigned short*)&a;
      const unsigned short* bp = (const unsigned short*)&bb;
#pragma unroll
      for (int j = 0; j < 8; ++j) {
        int d = c * 8 + j;
        *(unsigned int*)(dst + d * 104 + k0) =
            (unsigned int)ap[j] | ((unsigned int)bp[j] << 16);
      }
    }
  };

  stageK(Kb, Ks0);
  stageK(Kip, Ks1);
  stageVT(Vb, VT0);
  stageVT(Vip, VT1);

  // zero the per-wave P pad (k = 80..95) once; never overwritten afterwards
  {
    unsigned short* pw = Ps + wave * 16 * 104;
    int rr = lane >> 2, w4 = lane & 3;
    *(unsigned int*)(pw + rr * 104 + 80 + w4 * 4) = 0u;
    *(unsigned int*)(pw + rr * 104 + 82 + w4 * 4) = 0u;
  }
  __syncthreads();

  struct PVOut { f32x4 a[4]; float inv; };

  auto branch = [&](const unsigned short* KsL, const unsigned short* VTL) -> PVOut {
    // scores: ST[k][q], 5 k-tiles, accumulate over d (2 k-steps of 32)
    f32x4 st[5] = {};
#pragma unroll
    for (int t = 0; t < 5; ++t) {
      const unsigned short* kb = KsL + (t * 16 + l16) * 88 + quad * 8;
      bfrag8 k0 = *(const bfrag8*)(kb);
      bfrag8 k1 = *(const bfrag8*)(kb + 32);
      st[t] = __builtin_amdgcn_mfma_f32_16x16x32_bf16(k0, qf[0], st[t], 0, 0, 0);
      st[t] = __builtin_amdgcn_mfma_f32_16x16x32_bf16(k1, qf[1], st[t], 0, 0, 0);
    }
    // softmax over k = 16t + quad*4 + r  (mask k >= 77: t==4, quad==3, r>=1)
    float p[5][4];
    float m = -1e30f;
#pragma unroll
    for (int t = 0; t < 5; ++t)
#pragma unroll
      for (int r = 0; r < 4; ++r) {
        float s = st[t][r] * 0.125f;  // 1/sqrt(64)
        if (t == 4 && r >= 1) s = (quad == 3) ? -1e30f : s;
        p[t][r] = s;
        m = fmaxf(m, s);
      }
    m = fmaxf(m, __shfl_xor(m, 16, 64));
    m = fmaxf(m, __shfl_xor(m, 32, 64));
    float l = 0.f;
#pragma unroll
    for (int t = 0; t < 5; ++t)
#pragma unroll
      for (int r = 0; r < 4; ++r) {
        float e = __expf(p[t][r] - m);
        p[t][r] = e;
        l += e;
      }
    l += __shfl_xor(l, 16, 64);
    l += __shfl_xor(l, 32, 64);

    // write unnormalized P (bf16) to this wave's LDS tile: row q=l16
    unsigned short* prow = Ps + wave * 16 * 104 + l16 * 104 + quad * 4;
#pragma unroll
    for (int t = 0; t < 5; ++t) {
      __hip_bfloat162 h0 = __float22bfloat162_rn(make_float2(p[t][0], p[t][1]));
      __hip_bfloat162 h1 = __float22bfloat162_rn(make_float2(p[t][2], p[t][3]));
      unsigned int u0, u1;
      __builtin_memcpy(&u0, &h0, 4);
      __builtin_memcpy(&u1, &h1, 4);
      *(unsigned int*)(prow + t * 16) = u0;
      *(unsigned int*)(prow + t * 16 + 2) = u1;
    }
    __syncthreads();

    // PV: out[q][d], 4 d-tiles x 3 k-steps
    PVOut o;
    f32x4 acc[4] = {};
    const unsigned short* pbase = Ps + wave * 16 * 104 + l16 * 104;
#pragma unroll
    for (int ks = 0; ks < 3; ++ks) {
      bfrag8 pf = *(const bfrag8*)(pbase + ks * 32 + quad * 8);
#pragma unroll
      for (int dt = 0; dt < 4; ++dt) {
        bfrag8 vf = *(const bfrag8*)(VTL + (dt * 16 + l16) * 104 + ks * 32 + quad * 8);
        acc[dt] = __builtin_amdgcn_mfma_f32_16x16x32_bf16(pf, vf, acc[dt], 0, 0, 0);
      }
    }
#pragma unroll
    for (int dt = 0; dt < 4; ++dt) o.a[dt] = acc[dt];
    o.inv = 1.0f / l;
    return o;
  };

  PVOut o0 = branch(Ks0, VT0);
  __syncthreads();
  PVOut o1 = branch(Ks1, VT1);

  const float boost = boostp[0];
  // D layout: row q = quad*4 + r (within wave tile), col d = dt*16 + l16
#pragma unroll
  for (int r = 0; r < 4; ++r) {
    const int s = qb + wave * 16 + quad * 4 + r;
    const float sc = mask[s] * boost;
    const float i0 = __shfl(o0.inv, quad * 4 + r, 64);
    const float i1 = __shfl(o1.inv, quad * 4 + r, 64);
    unsigned short* op = hs + (size_t)(b * S_ + s) * D_ + h * HD_ + l16;
#pragma unroll
    for (int dt = 0; dt < 4; ++dt) {
      float v = o0.a[dt][r] * i0 + sc * (o1.a[dt][r] * i1);
      op[dt * 16] = f2bf(v);
    }
  }
}

// ---------------------------------------------------------------------------
extern "C" void kernel_launch(void* const* d_in, const int* in_sizes, int n_in,
                              void* d_out, int out_size, void* d_ws, size_t ws_size,
                              hipStream_t stream) {
  const float* hidden = (const float*)d_in[0];
  const float* enc    = (const float*)d_in[1];
  const float* mask   = (const float*)d_in[2];
  const float* Wq     = (const float*)d_in[3];
  const float* Wk     = (const float*)d_in[4];
  const float* Wv     = (const float*)d_in[5];
  const float* Wkip   = (const float*)d_in[6];
  const float* Wvip   = (const float*)d_in[7];
  const float* Wo     = (const float*)d_in[8];
  const float* bo     = (const float*)d_in[9];

  char* ws = (char*)d_ws;
  unsigned short* cHid  = (unsigned short*)(ws + 0ULL);           // 41,943,040
  unsigned short* hsb   = cHid;                                   // alias (cHid dead after Q-proj)
  unsigned short* cEnc  = (unsigned short*)(ws + 41943040ULL);
  unsigned short* cWqT  = (unsigned short*)(ws + 43204608ULL);    // [N,K] transposed
  unsigned short* cWk   = (unsigned short*)(ws + 46481408ULL);
  unsigned short* cWv   = (unsigned short*)(ws + 51724288ULL);
  unsigned short* cWkip = (unsigned short*)(ws + 56967168ULL);
  unsigned short* cWvip = (unsigned short*)(ws + 62210048ULL);
  unsigned short* cWoT  = (unsigned short*)(ws + 67452928ULL);    // [N,K] transposed
  unsigned short* Qb    = (unsigned short*)(ws + 70729728ULL);
  unsigned short* Kb    = (unsigned short*)(ws + 112672768ULL);
  unsigned short* Vb    = (unsigned short*)(ws + 113461248ULL);
  unsigned short* Kip   = (unsigned short*)(ws + 114249728ULL);
  unsigned short* Vip   = (unsigned short*)(ws + 115038208ULL);
  float* boostp         = (float*)(ws + 115826688ULL);

  struct CvtJob { const float* src; unsigned short* dst; int n; };
  const CvtJob jobs[6] = {
      {hidden, cHid, B_ * S_ * D_},  {enc, cEnc, B_ * SKV_ * CD_},
      {Wk, cWk, CD_ * D_},           {Wv, cWv, CD_ * D_},
      {Wkip, cWkip, CD_ * D_},       {Wvip, cWvip, CD_ * D_}};
  for (int i = 0; i < 6; ++i) {
    int n4 = jobs[i].n >> 2;
    int g = (n4 + 255) / 256; if (g > 4096) g = 4096;
    convert_k<<<dim3(g), dim3(256), 0, stream>>>(jobs[i].src, jobs[i].dst, n4);
  }
  // transposed weights for the two big GEMMs (B^T operand for m97 structure)
  convtr_k<<<dim3(D_ / 32, D_ / 32), dim3(256), 0, stream>>>(Wq, cWqT, D_, D_);
  convtr_k<<<dim3(D_ / 32, D_ / 32), dim3(256), 0, stream>>>(Wo, cWoT, D_, D_);

  boost_k<<<dim3(1), dim3(256), 0, stream>>>(mask, boostp);

  const int MQ = B_ * S_;    // 16384
  const int MKV = B_ * SKV_; // 308

  // Q = hidden @ Wq  (128-tile async GEMM; 16384/1280/1280 all tile-exact)
  gemm_bt128<<<dim3(MQ / 128, D_ / 128), dim3(256), 0, stream>>>(
      cHid, cWqT, Qb, MQ, D_, D_, nullptr, 0);

  gemm_bf16<<<dim3(5, 20), dim3(256), 0, stream>>>(cEnc, cWk, Kb, MKV, D_, CD_);
  gemm_bf16<<<dim3(5, 20), dim3(256), 0, stream>>>(cEnc, cWv, Vb, MKV, D_, CD_);
  gemm_bf16<<<dim3(5, 20), dim3(256), 0, stream>>>(cEnc, cWkip, Kip, MKV, D_, CD_);
  gemm_bf16<<<dim3(5, 20), dim3(256), 0, stream>>>(cEnc, cWvip, Vip, MKV, D_, CD_);

  attn_k<<<dim3(S_ / 64, B_ * H_), dim3(256), 0, stream>>>(Qb, Kb, Vb, Kip, Vip,
                                                           mask, boostp, hsb);

  // out = hsb @ Wo + bo  (fp32 output)
  gemm_bt128<<<dim3(MQ / 128, D_ / 128), dim3(256), 0, stream>>>(
      hsb, cWoT, d_out, MQ, D_, D_, bo, 1);
}

// Round 3
// 502.743 us; speedup vs baseline: 1.7605x; 1.3133x over previous
//
#include <hip/hip_runtime.h>
#include <hip/hip_bf16.h>
#include <stdint.h>

// Problem constants
#define B_   4
#define S_   4096
#define D_   1280
#define H_   20
#define HD_  64
#define SKV_ 77
#define CD_  2048

typedef short bfrag8 __attribute__((ext_vector_type(8)));   // 8 bf16 = 4 VGPRs
typedef float f32x4  __attribute__((ext_vector_type(4)));

__device__ __forceinline__ float bf2f(unsigned short h) {
  return __uint_as_float(((unsigned int)h) << 16);
}
__device__ __forceinline__ unsigned short f2bf(float f) {
  unsigned int u = __float_as_uint(f);
  unsigned int r = (u + 0x7FFFu + ((u >> 16) & 1u)) >> 16;  // RNE
  return (unsigned short)r;
}
__device__ __forceinline__ float cvtlo(unsigned int u) { return __uint_as_float(u << 16); }
__device__ __forceinline__ float cvthi(unsigned int u) { return __uint_as_float(u & 0xFFFF0000u); }

// async global->LDS, 16B per lane. LDS dest = wave-uniform base + lane*16.
__device__ __forceinline__ void async16(const unsigned short* g, unsigned short* l) {
  __builtin_amdgcn_global_load_lds(
      (const __attribute__((address_space(1))) unsigned int*)g,
      (__attribute__((address_space(3))) unsigned int*)l, 16, 0, 0);
}

// ---------------------------------------------------------------------------
// fp32 -> bf16 conversion (vectorized)
// ---------------------------------------------------------------------------
__global__ __launch_bounds__(256) void convert_k(const float* __restrict__ src,
                                                 unsigned short* __restrict__ dst,
                                                 int n4) {
  for (int i = blockIdx.x * 256 + threadIdx.x; i < n4; i += gridDim.x * 256) {
    float4 v = ((const float4*)src)[i];
    uint2 o;
    o.x = (unsigned int)f2bf(v.x) | ((unsigned int)f2bf(v.y) << 16);
    o.y = (unsigned int)f2bf(v.z) | ((unsigned int)f2bf(v.w) << 16);
    ((uint2*)dst)[i] = o;
  }
}

// 4 same-size conversions in one launch (blockIdx.y selects job)
struct Cvt4 { const float* s[4]; unsigned short* d[4]; };
__global__ __launch_bounds__(256) void convert4_k(Cvt4 j, int n4) {
  const float* __restrict__ src = j.s[blockIdx.y];
  unsigned short* __restrict__ dst = j.d[blockIdx.y];
  for (int i = blockIdx.x * 256 + threadIdx.x; i < n4; i += gridDim.x * 256) {
    float4 v = ((const float4*)src)[i];
    uint2 o;
    o.x = (unsigned int)f2bf(v.x) | ((unsigned int)f2bf(v.y) << 16);
    o.y = (unsigned int)f2bf(v.z) | ((unsigned int)f2bf(v.w) << 16);
    ((uint2*)dst)[i] = o;
  }
}

// ---------------------------------------------------------------------------
// fp32 [K,N] -> bf16 transposed [N,K], 32x32 LDS tile (both sides coalesced)
// ---------------------------------------------------------------------------
__global__ __launch_bounds__(256) void convtr_k(const float* __restrict__ src,
                                                unsigned short* __restrict__ dst,
                                                int K, int N) {
  __shared__ float t[32][33];
  const int k0 = blockIdx.x * 32, n0 = blockIdx.y * 32;
  const int r = threadIdx.x >> 3, c4 = threadIdx.x & 7;
  float4 v = *(const float4*)(src + (size_t)(k0 + r) * N + n0 + c4 * 4);
  t[r][c4 * 4 + 0] = v.x; t[r][c4 * 4 + 1] = v.y;
  t[r][c4 * 4 + 2] = v.z; t[r][c4 * 4 + 3] = v.w;
  __syncthreads();
  uint2 o;
  o.x = (unsigned int)f2bf(t[c4 * 4 + 0][r]) | ((unsigned int)f2bf(t[c4 * 4 + 1][r]) << 16);
  o.y = (unsigned int)f2bf(t[c4 * 4 + 2][r]) | ((unsigned int)f2bf(t[c4 * 4 + 3][r]) << 16);
  *(uint2*)(dst + (size_t)(n0 + r) * K + k0 + c4 * 4) = o;
}

// ---------------------------------------------------------------------------
// boost scalar
// ---------------------------------------------------------------------------
__global__ __launch_bounds__(256) void boost_k(const float* __restrict__ mask,
                                               float* __restrict__ outp) {
  __shared__ float red[4];
  float s = 0.f;
  for (int i = threadIdx.x; i < S_; i += 256) s += mask[i];
#pragma unroll
  for (int off = 32; off > 0; off >>= 1) s += __shfl_down(s, off, 64);
  int wave = threadIdx.x >> 6, lane = threadIdx.x & 63;
  if (lane == 0) red[wave] = s;
  __syncthreads();
  if (threadIdx.x == 0) {
    float t = red[0] + red[1] + red[2] + red[3];
    float ratio = t * (1.0f / (float)S_);
    float boost = (ratio > 1e-6f && ratio < 0.1f)
                      ? fminf(1.0f + (0.1f - ratio) * 30.0f, 4.0f)
                      : 1.0f;
    outp[0] = boost;
  }
}

// ---------------------------------------------------------------------------
// Phased counted-vmcnt GEMM: C[M,N] = A[M,K] @ Bt[N,K]^T (+bias).
// BM=256 BN=128 BK=32. 512 threads = 8 waves (4M x 2N), per-wave 64x64.
// 3 LDS buffers (72 KB -> 2 blocks/CU), prefetch distance 2 K-tiles,
// s_waitcnt vmcnt(3) at tile boundaries (never 0 in steady state), raw
// s_barrier (no __syncthreads drain), setprio(1) around MFMA clusters.
// T2 chunk swizzle (c' = (c + (r>>1)) & 3) applied BOTH sides: pre-swizzled
// global source (LDS dest linear for global_load_lds) + swizzled ds_read
// chunk -> conflict-free per 8-lane octet.
// __launch_bounds__(512,3): ~170-reg budget => zero in-loop spill risk
// (scratch VMEM would corrupt the hand-counted vmcnt). Occupancy is
// LDS-capped at 2 blocks/CU regardless (72 KB/block).
// Requires M%256==0, N%128==0, K%32==0, K/32 >= 3, grid%8==0.
// ---------------------------------------------------------------------------
__global__ __launch_bounds__(512, 3) void gemm8p(
    const unsigned short* __restrict__ A, const unsigned short* __restrict__ Bt,
    void* __restrict__ C, int M, int N, int K,
    const float* __restrict__ bias, int f32out) {
  __shared__ unsigned short Asm[3 * 256 * 32];  // 49152 B
  __shared__ unsigned short Bsm[3 * 128 * 32];  // 24576 B

  const int tid = threadIdx.x;
  const int nb = N >> 7;  // N/128
  int wg = blockIdx.x;
  {  // XCD-aware swizzle (grid % 8 == 0 at all call sites: 640)
    int cpx = gridDim.x >> 3;
    wg = (wg & 7) * cpx + (wg >> 3);
  }
  const int m0 = (wg / nb) * 256, n0 = (wg % nb) * 128;

  const int wave = tid >> 6, lane = tid & 63;
  const int wm = (wave >> 1) * 64, wn = (wave & 1) * 64;
  const int l16 = lane & 15, quad = lane >> 4;

  // staging decomposition: chunk c = tid -> row r0 = tid>>2, k-chunk kc = tid&3
  const int r0 = tid >> 2;
  // swizzled global k-chunk for this thread's LDS slot (constant per thread)
  const int gch = ((tid & 3) - (tid >> 3)) & 3;
  // swizzled ds_read chunk (constant per lane; (row>>1)&3 == (l16>>1)&3)
  const int ch = (quad + (l16 >> 1)) & 3;

  const unsigned short* srcA = A + (size_t)(m0 + r0) * K + gch * 8;
  const unsigned short* srcB = Bt + (size_t)(n0 + r0) * K + gch * 8;

  unsigned short* pa0 = Asm;
  unsigned short* pa1 = Asm + 256 * 32;
  unsigned short* pa2 = Asm + 2 * 256 * 32;
  unsigned short* pb0 = Bsm;
  unsigned short* pb1 = Bsm + 128 * 32;
  unsigned short* pb2 = Bsm + 2 * 128 * 32;

  const int NT = K >> 5;

  // per-tile staging: A = 2 loads/thread, B = 1 load/thread (3 vmcnt units)
  auto stageA = [&](unsigned short* dst, int t) {
    const unsigned short* s = srcA + t * 32;
    async16(s, dst + tid * 8);
    async16(s + (size_t)128 * K, dst + (512 + tid) * 8);
  };
  auto stageB = [&](unsigned short* dst, int t) {
    async16(srcB + t * 32, dst + tid * 8);
  };

  f32x4 acc[4][4] = {};

  // prologue: stage tiles 0 and 1
  stageA(pa0, 0); stageB(pb0, 0);
  stageA(pa1, 1); stageB(pb1, 1);
  asm volatile("s_waitcnt vmcnt(3)" ::: "memory");  // tile 0 landed
  __builtin_amdgcn_s_barrier();

  for (int t = 0; t < NT; ++t) {
    const bool pre = (t + 2) < NT;
    // ---- phase A: frags m0,m1 + all B frags; issue A-prefetch of t+2
    bfrag8 af0 = *(const bfrag8*)(pa0 + (wm + 0 * 16 + l16) * 32 + ch * 8);
    bfrag8 af1 = *(const bfrag8*)(pa0 + (wm + 1 * 16 + l16) * 32 + ch * 8);
    bfrag8 bf[4];
#pragma unroll
    for (int nt = 0; nt < 4; ++nt)
      bf[nt] = *(const bfrag8*)(pb0 + (wn + nt * 16 + l16) * 32 + ch * 8);
    if (pre) stageA(pa2, t + 2);
    __builtin_amdgcn_s_barrier();
    __builtin_amdgcn_s_setprio(1);
#pragma unroll
    for (int nt = 0; nt < 4; ++nt) {
      acc[0][nt] = __builtin_amdgcn_mfma_f32_16x16x32_bf16(af0, bf[nt], acc[0][nt], 0, 0, 0);
      acc[1][nt] = __builtin_amdgcn_mfma_f32_16x16x32_bf16(af1, bf[nt], acc[1][nt], 0, 0, 0);
    }
    __builtin_amdgcn_s_setprio(0);
    __builtin_amdgcn_s_barrier();
    // ---- phase B: frags m2,m3; issue B-prefetch of t+2
    bfrag8 af2 = *(const bfrag8*)(pa0 + (wm + 2 * 16 + l16) * 32 + ch * 8);
    bfrag8 af3 = *(const bfrag8*)(pa0 + (wm + 3 * 16 + l16) * 32 + ch * 8);
    if (pre) stageB(pb2, t + 2);
    __builtin_amdgcn_s_barrier();
    __builtin_amdgcn_s_setprio(1);
#pragma unroll
    for (int nt = 0; nt < 4; ++nt) {
      acc[2][nt] = __builtin_amdgcn_mfma_f32_16x16x32_bf16(af2, bf[nt], acc[2][nt], 0, 0, 0);
      acc[3][nt] = __builtin_amdgcn_mfma_f32_16x16x32_bf16(af3, bf[nt], acc[3][nt], 0, 0, 0);
    }
    __builtin_amdgcn_s_setprio(0);
    // ---- tile boundary: ensure tile t+1 DMA landed (counted, not drain)
    if (t + 1 < NT) {
      if (pre) { asm volatile("s_waitcnt vmcnt(3)" ::: "memory"); }
      else     { asm volatile("s_waitcnt vmcnt(0)" ::: "memory"); }
      __builtin_amdgcn_s_barrier();
      unsigned short* ta = pa0; pa0 = pa1; pa1 = pa2; pa2 = ta;
      unsigned short* tb = pb0; pb0 = pb1; pb1 = pb2; pb2 = tb;
    }
  }

  // epilogue: D row = quad*4 + r, col = lane&15
#pragma unroll
  for (int mt = 0; mt < 4; ++mt) {
#pragma unroll
    for (int nt = 0; nt < 4; ++nt) {
#pragma unroll
      for (int r = 0; r < 4; ++r) {
        int row = m0 + wm + mt * 16 + quad * 4 + r;
        int col = n0 + wn + nt * 16 + l16;
        float v = acc[mt][nt][r];
        if (bias) v += bias[col];
        if (f32out) ((float*)C)[(size_t)row * N + col] = v;
        else ((unsigned short*)C)[(size_t)row * N + col] = f2bf(v);
      }
    }
  }
}

// ---------------------------------------------------------------------------
// small GEMM for the 4 KV projections (M=308), merged into one launch:
// blockIdx.z selects weight/output. 64x64 tile, bounds-checked M.
// ---------------------------------------------------------------------------
struct KVArgs { const unsigned short* W[4]; unsigned short* O[4]; };
__global__ __launch_bounds__(256) void gemm_kv4(
    const unsigned short* __restrict__ A, KVArgs kv, int M, int N, int K) {
  const unsigned short* __restrict__ Bw = kv.W[blockIdx.z];
  unsigned short* __restrict__ C = kv.O[blockIdx.z];
  __shared__ unsigned short As[64][40];
  __shared__ unsigned short Bs[64][40];

  const int tid = threadIdx.x;
  const int m0 = blockIdx.x * 64, n0 = blockIdx.y * 64;
  const int wave = tid >> 6, lane = tid & 63;
  const int l16 = lane & 15, quad = lane >> 4;

  f32x4 acc[4] = {};

  for (int k0 = 0; k0 < K; k0 += 32) {
    {
      int row = tid >> 2, kc = tid & 3;
      int gr = m0 + row;
      uint4 v = make_uint4(0u, 0u, 0u, 0u);
      if (gr < M) v = *(const uint4*)(A + (size_t)gr * K + k0 + kc * 8);
      *(uint4*)&As[row][kc * 8] = v;
    }
    {
      int kk = tid >> 3, n8 = tid & 7;
      uint4 v = *(const uint4*)(Bw + (size_t)(k0 + kk) * N + n0 + n8 * 8);
      unsigned short* p = (unsigned short*)&v;
#pragma unroll
      for (int j = 0; j < 8; ++j) Bs[n8 * 8 + j][kk] = p[j];
    }
    __syncthreads();

    bfrag8 af = *(const bfrag8*)&As[wave * 16 + l16][quad * 8];
#pragma unroll
    for (int nt = 0; nt < 4; ++nt) {
      bfrag8 bf = *(const bfrag8*)&Bs[nt * 16 + l16][quad * 8];
      acc[nt] = __builtin_amdgcn_mfma_f32_16x16x32_bf16(af, bf, acc[nt], 0, 0, 0);
    }
    __syncthreads();
  }

#pragma unroll
  for (int nt = 0; nt < 4; ++nt) {
#pragma unroll
    for (int r = 0; r < 4; ++r) {
      int row = m0 + wave * 16 + quad * 4 + r;
      if (row < M) {
        int col = n0 + nt * 16 + l16;
        C[(size_t)row * N + col] = f2bf(acc[nt][r]);
      }
    }
  }
}

// ---------------------------------------------------------------------------
// Attention v4: MFMA-based. One block = 64 q-rows of one (b,h); 4 waves, each
// wave owns 16 q-rows. SKV=77 padded to 80 (scores) / 96 (PV k-steps).
// ---------------------------------------------------------------------------
__global__ __launch_bounds__(256, 2) void attn_k(
    const unsigned short* __restrict__ Q, const unsigned short* __restrict__ Kb,
    const unsigned short* __restrict__ Vb, const unsigned short* __restrict__ Kip,
    const unsigned short* __restrict__ Vip, const float* __restrict__ mask,
    const float* __restrict__ boostp, unsigned short* __restrict__ hs) {
  __shared__ unsigned short Ks0[80 * 88];    // 14080 B, row k stride 88 (2-way max)
  __shared__ unsigned short Ks1[80 * 88];
  __shared__ unsigned short VT0[64 * 104];   // 13312 B, row d stride 104 (2-way max)
  __shared__ unsigned short VT1[64 * 104];
  __shared__ unsigned short Ps[4 * 16 * 104];  // per-wave P tile [16 q][104 k]

  const int tid = threadIdx.x;
  const int bh = blockIdx.y;
  const int b = bh / H_, h = bh % H_;
  const int qb = blockIdx.x * 64;
  const int wave = tid >> 6, lane = tid & 63;
  const int l16 = lane & 15, quad = lane >> 4;

  bfrag8 qf[2];
  {
    const unsigned short* qp =
        Q + (size_t)(b * S_ + qb + wave * 16 + l16) * D_ + h * HD_ + quad * 8;
    qf[0] = *(const bfrag8*)(qp);
    qf[1] = *(const bfrag8*)(qp + 32);
  }

  auto stageK = [&](const unsigned short* src, unsigned short* dst) {
    for (int idx = tid; idx < 640; idx += 256) {
      int row = idx >> 3, c = idx & 7;
      uint4 v = make_uint4(0u, 0u, 0u, 0u);
      if (row < SKV_)
        v = *(const uint4*)(src + (size_t)(b * SKV_ + row) * D_ + h * HD_ + c * 8);
      *(uint4*)(dst + row * 88 + c * 8) = v;
    }
  };
  auto stageVT = [&](const unsigned short* src, unsigned short* dst) {
    for (int idx = tid; idx < 384; idx += 256) {
      int kp = idx % 48, c = idx / 48;
      int k0 = kp * 2;
      uint4 a = make_uint4(0u, 0u, 0u, 0u), bb = make_uint4(0u, 0u, 0u, 0u);
      if (k0 < SKV_)
        a = *(const uint4*)(src + (size_t)(b * SKV_ + k0) * D_ + h * HD_ + c * 8);
      if (k0 + 1 < SKV_)
        bb = *(const uint4*)(src + (size_t)(b * SKV_ + k0 + 1) * D_ + h * HD_ + c * 8);
      const unsigned short* ap = (const unsigned short*)&a;
      const unsigned short* bp = (const unsigned short*)&bb;
#pragma unroll
      for (int j = 0; j < 8; ++j) {
        int d = c * 8 + j;
        *(unsigned int*)(dst + d * 104 + k0) =
            (unsigned int)ap[j] | ((unsigned int)bp[j] << 16);
      }
    }
  };

  stageK(Kb, Ks0);
  stageK(Kip, Ks1);
  stageVT(Vb, VT0);
  stageVT(Vip, VT1);

  {
    unsigned short* pw = Ps + wave * 16 * 104;
    int rr = lane >> 2, w4 = lane & 3;
    *(unsigned int*)(pw + rr * 104 + 80 + w4 * 4) = 0u;
    *(unsigned int*)(pw + rr * 104 + 82 + w4 * 4) = 0u;
  }
  __syncthreads();

  struct PVOut { f32x4 a[4]; float inv; };

  auto branch = [&](const unsigned short* KsL, const unsigned short* VTL) -> PVOut {
    f32x4 st[5] = {};
#pragma unroll
    for (int t = 0; t < 5; ++t) {
      const unsigned short* kb = KsL + (t * 16 + l16) * 88 + quad * 8;
      bfrag8 k0 = *(const bfrag8*)(kb);
      bfrag8 k1 = *(const bfrag8*)(kb + 32);
      st[t] = __builtin_amdgcn_mfma_f32_16x16x32_bf16(k0, qf[0], st[t], 0, 0, 0);
      st[t] = __builtin_amdgcn_mfma_f32_16x16x32_bf16(k1, qf[1], st[t], 0, 0, 0);
    }
    float p[5][4];
    float m = -1e30f;
#pragma unroll
    for (int t = 0; t < 5; ++t)
#pragma unroll
      for (int r = 0; r < 4; ++r) {
        float s = st[t][r] * 0.125f;
        if (t == 4 && r >= 1) s = (quad == 3) ? -1e30f : s;
        p[t][r] = s;
        m = fmaxf(m, s);
      }
    m = fmaxf(m, __shfl_xor(m, 16, 64));
    m = fmaxf(m, __shfl_xor(m, 32, 64));
    float l = 0.f;
#pragma unroll
    for (int t = 0; t < 5; ++t)
#pragma unroll
      for (int r = 0; r < 4; ++r) {
        float e = __expf(p[t][r] - m);
        p[t][r] = e;
        l += e;
      }
    l += __shfl_xor(l, 16, 64);
    l += __shfl_xor(l, 32, 64);

    unsigned short* prow = Ps + wave * 16 * 104 + l16 * 104 + quad * 4;
#pragma unroll
    for (int t = 0; t < 5; ++t) {
      __hip_bfloat162 h0 = __float22bfloat162_rn(make_float2(p[t][0], p[t][1]));
      __hip_bfloat162 h1 = __float22bfloat162_rn(make_float2(p[t][2], p[t][3]));
      unsigned int u0, u1;
      __builtin_memcpy(&u0, &h0, 4);
      __builtin_memcpy(&u1, &h1, 4);
      *(unsigned int*)(prow + t * 16) = u0;
      *(unsigned int*)(prow + t * 16 + 2) = u1;
    }
    __syncthreads();

    PVOut o;
    f32x4 acc[4] = {};
    const unsigned short* pbase = Ps + wave * 16 * 104 + l16 * 104;
#pragma unroll
    for (int ks = 0; ks < 3; ++ks) {
      bfrag8 pf = *(const bfrag8*)(pbase + ks * 32 + quad * 8);
#pragma unroll
      for (int dt = 0; dt < 4; ++dt) {
        bfrag8 vf = *(const bfrag8*)(VTL + (dt * 16 + l16) * 104 + ks * 32 + quad * 8);
        acc[dt] = __builtin_amdgcn_mfma_f32_16x16x32_bf16(pf, vf, acc[dt], 0, 0, 0);
      }
    }
#pragma unroll
    for (int dt = 0; dt < 4; ++dt) o.a[dt] = acc[dt];
    o.inv = 1.0f / l;
    return o;
  };

  PVOut o0 = branch(Ks0, VT0);
  __syncthreads();
  PVOut o1 = branch(Ks1, VT1);

  const float boost = boostp[0];
#pragma unroll
  for (int r = 0; r < 4; ++r) {
    const int s = qb + wave * 16 + quad * 4 + r;
    const float sc = mask[s] * boost;
    const float i0 = __shfl(o0.inv, quad * 4 + r, 64);
    const float i1 = __shfl(o1.inv, quad * 4 + r, 64);
    unsigned short* op = hs + (size_t)(b * S_ + s) * D_ + h * HD_ + l16;
#pragma unroll
    for (int dt = 0; dt < 4; ++dt) {
      float v = o0.a[dt][r] * i0 + sc * (o1.a[dt][r] * i1);
      op[dt * 16] = f2bf(v);
    }
  }
}

// ---------------------------------------------------------------------------
extern "C" void kernel_launch(void* const* d_in, const int* in_sizes, int n_in,
                              void* d_out, int out_size, void* d_ws, size_t ws_size,
                              hipStream_t stream) {
  const float* hidden = (const float*)d_in[0];
  const float* enc    = (const float*)d_in[1];
  const float* mask   = (const float*)d_in[2];
  const float* Wq     = (const float*)d_in[3];
  const float* Wk     = (const float*)d_in[4];
  const float* Wv     = (const float*)d_in[5];
  const float* Wkip   = (const float*)d_in[6];
  const float* Wvip   = (const float*)d_in[7];
  const float* Wo     = (const float*)d_in[8];
  const float* bo     = (const float*)d_in[9];

  char* ws = (char*)d_ws;
  unsigned short* cHid  = (unsigned short*)(ws + 0ULL);           // 41,943,040
  unsigned short* hsb   = cHid;                                   // alias (cHid dead after Q-proj)
  unsigned short* cEnc  = (unsigned short*)(ws + 41943040ULL);
  unsigned short* cWqT  = (unsigned short*)(ws + 43204608ULL);    // [N,K] transposed
  unsigned short* cWk   = (unsigned short*)(ws + 46481408ULL);
  unsigned short* cWv   = (unsigned short*)(ws + 51724288ULL);
  unsigned short* cWkip = (unsigned short*)(ws + 56967168ULL);
  unsigned short* cWvip = (unsigned short*)(ws + 62210048ULL);
  unsigned short* cWoT  = (unsigned short*)(ws + 67452928ULL);    // [N,K] transposed
  unsigned short* Qb    = (unsigned short*)(ws + 70729728ULL);
  unsigned short* Kb    = (unsigned short*)(ws + 112672768ULL);
  unsigned short* Vb    = (unsigned short*)(ws + 113461248ULL);
  unsigned short* Kip   = (unsigned short*)(ws + 114249728ULL);
  unsigned short* Vip   = (unsigned short*)(ws + 115038208ULL);
  float* boostp         = (float*)(ws + 115826688ULL);

  // big converts (hidden, enc)
  {
    int n4 = (B_ * S_ * D_) >> 2;
    int g = (n4 + 255) / 256; if (g > 4096) g = 4096;
    convert_k<<<dim3(g), dim3(256), 0, stream>>>(hidden, cHid, n4);
  }
  {
    int n4 = (B_ * SKV_ * CD_) >> 2;
    int g = (n4 + 255) / 256;
    convert_k<<<dim3(g), dim3(256), 0, stream>>>(enc, cEnc, n4);
  }
  // 4 same-size weight converts in one launch
  {
    Cvt4 j;
    j.s[0] = Wk;   j.d[0] = cWk;
    j.s[1] = Wv;   j.d[1] = cWv;
    j.s[2] = Wkip; j.d[2] = cWkip;
    j.s[3] = Wvip; j.d[3] = cWvip;
    int n4 = (CD_ * D_) >> 2;
    int g = (n4 + 255) / 256; if (g > 4096) g = 4096;
    convert4_k<<<dim3(g, 4), dim3(256), 0, stream>>>(j, n4);
  }
  // transposed weights for the two big GEMMs
  convtr_k<<<dim3(D_ / 32, D_ / 32), dim3(256), 0, stream>>>(Wq, cWqT, D_, D_);
  convtr_k<<<dim3(D_ / 32, D_ / 32), dim3(256), 0, stream>>>(Wo, cWoT, D_, D_);

  boost_k<<<dim3(1), dim3(256), 0, stream>>>(mask, boostp);

  const int MQ = B_ * S_;    // 16384
  const int MKV = B_ * SKV_; // 308

  // Q = hidden @ Wq  (phased GEMM; 16384%256==0, 1280%128==0, 1280%32==0)
  gemm8p<<<dim3((MQ / 256) * (D_ / 128)), dim3(512), 0, stream>>>(
      cHid, cWqT, Qb, MQ, D_, D_, nullptr, 0);

  // 4 KV projections in one launch
  {
    KVArgs kv;
    kv.W[0] = cWk;   kv.O[0] = Kb;
    kv.W[1] = cWv;   kv.O[1] = Vb;
    kv.W[2] = cWkip; kv.O[2] = Kip;
    kv.W[3] = cWvip; kv.O[3] = Vip;
    gemm_kv4<<<dim3(5, 20, 4), dim3(256), 0, stream>>>(cEnc, kv, MKV, D_, CD_);
  }

  attn_k<<<dim3(S_ / 64, B_ * H_), dim3(256), 0, stream>>>(Qb, Kb, Vb, Kip, Vip,
                                                           mask, boostp, hsb);

  // out = hsb @ Wo + bo  (fp32 output)
  gemm8p<<<dim3((MQ / 256) * (D_ / 128)), dim3(512), 0, stream>>>(
      hsb, cWoT, d_out, MQ, D_, D_, bo, 1);
}